// Round 1
// baseline (98.068 us; speedup 1.0000x reference)
//
#include <hip/hip_runtime.h>
#include <math.h>

// Problem constants (from reference):
//   B=4, N=1024 -> 4096 atoms; IN_CH=OUT_CH=16; N_BASIS=16; N_FEAT=19
//   MAX_RADIUS=3.5; GAMMA=3.5/16; centers = linspace(0,3.5,16) -> c_f = f*3.5/15
//   out /= sqrt(24)
#define IN_CH 16
#define OUT_CH 16
#define N_BASIS 16
#define N_FEAT 19               // 16 basis + 3 rhat
#define Y_STRIDE (N_FEAT * OUT_CH)   // 304 floats per atom
#define MAX_RADIUS 3.5f
#define GAMMA_INV (16.0f / 3.5f)     // 1/GAMMA
#define CENTER_STEP (3.5f / 15.0f)
#define INV_SQRT_NNORM 0.20412414523193154f  // 1/sqrt(24)

// ---------------------------------------------------------------------------
// Kernel A: per-atom pre-contraction  y[a, f, o] = sum_i W[f,o,i] * x[a,i]
// One block per atom; threads t in [0,304) handle (f,o) = (t/16, t%16).
// W row W[f,o,:] is contiguous (16 floats) -> vectorizable, L1/L2 resident.
// ---------------------------------------------------------------------------
__global__ __launch_bounds__(320) void precompute_y(
    const float* __restrict__ x, const float* __restrict__ W,
    float* __restrict__ y, int n_atoms) {
  __shared__ float xs[IN_CH];
  const int a = blockIdx.x;
  const int t = threadIdx.x;
  if (t < IN_CH) xs[t] = x[a * IN_CH + t];
  __syncthreads();
  if (t < Y_STRIDE) {
    const float4* w4 = (const float4*)(W + t * IN_CH);
    float acc = 0.f;
#pragma unroll
    for (int q = 0; q < 4; ++q) {
      float4 w = w4[q];
      acc += w.x * xs[4 * q + 0] + w.y * xs[4 * q + 1] +
             w.z * xs[4 * q + 2] + w.w * xs[4 * q + 3];
    }
    y[(size_t)a * Y_STRIDE + t] = acc;
  }
}

// ---------------------------------------------------------------------------
// Kernel B: per-edge  msg[e,o] = sum_f feat[e,f] * y[src_e, f, o]
// 16 lanes per edge (one per output channel), 16 edges per 256-thread block.
// Lane o computes basis feature o (one __expf each); lanes 0..2 add rhat.
// Features shared through LDS; y reads are 64B-coalesced per edge group.
// One fp32 atomicAdd per (edge, channel) into out[dst*16+o].
// ---------------------------------------------------------------------------
__global__ __launch_bounds__(256) void edge_scatter(
    const float* __restrict__ y, const float* __restrict__ edge_vec,
    const int* __restrict__ edge_src, const int* __restrict__ edge_dst,
    float* __restrict__ out, int E) {
  __shared__ float feat[16][N_FEAT];

  const int t = threadIdx.x;
  const int eg = t >> 4;   // edge slot within block, 0..15
  const int o = t & 15;    // output channel / basis index
  const int e = blockIdx.x * 16 + eg;
  const bool valid = (e < E);

  float vx = 0.f, vy = 0.f, vz = 0.f;
  int src = 0, dst = 0;
  if (valid) {
    vx = edge_vec[3 * e + 0];
    vy = edge_vec[3 * e + 1];
    vz = edge_vec[3 * e + 2];
    src = edge_src[e];
    dst = edge_dst[e];
  }
  const float r2 = vx * vx + vy * vy + vz * vz;
  const float r = sqrtf(r2);

  // basis feature o: exp(-((r - c_o)/gamma)^2)
  const float tt = (r - CENTER_STEP * (float)o) * GAMMA_INV;
  feat[eg][o] = __expf(-tt * tt);
  if (o < 3) {
    // reference: rhat = where(r > 1e-10, vec / max(r,1e-10), 0)
    const float inv = (r > 1e-10f) ? (1.0f / r) : 0.0f;
    const float comp = (o == 0) ? vx : ((o == 1) ? vy : vz);
    feat[eg][N_BASIS + o] = comp * inv;
  }
  __syncthreads();

  if (valid) {
    const float* __restrict__ yrow = y + (size_t)src * Y_STRIDE + o;
    float acc = 0.f;
#pragma unroll
    for (int f = 0; f < N_FEAT; ++f) acc += feat[eg][f] * yrow[f * OUT_CH];
    atomicAdd(&out[dst * OUT_CH + o], acc * INV_SQRT_NNORM);
  }
}

// ---------------------------------------------------------------------------
// Fallback (only if ws_size is too small for y): direct per-edge evaluation
// with W staged in LDS. ~5k MACs/edge but always correct.
// ---------------------------------------------------------------------------
__global__ __launch_bounds__(256) void edge_direct(
    const float* __restrict__ x, const float* __restrict__ W,
    const float* __restrict__ edge_vec, const int* __restrict__ edge_src,
    const int* __restrict__ edge_dst, float* __restrict__ out, int E) {
  __shared__ float Ws[N_FEAT * OUT_CH * IN_CH];  // 4864 floats = 19 KB
  __shared__ float feat[16][N_FEAT];
  __shared__ float xs[16][IN_CH];

  const int t = threadIdx.x;
  for (int i = t; i < N_FEAT * OUT_CH * IN_CH; i += 256) Ws[i] = W[i];

  const int eg = t >> 4;
  const int o = t & 15;
  const int e = blockIdx.x * 16 + eg;
  const bool valid = (e < E);

  float vx = 0.f, vy = 0.f, vz = 0.f;
  int src = 0, dst = 0;
  if (valid) {
    vx = edge_vec[3 * e + 0];
    vy = edge_vec[3 * e + 1];
    vz = edge_vec[3 * e + 2];
    src = edge_src[e];
    dst = edge_dst[e];
    xs[eg][o] = x[src * IN_CH + o];
  }
  const float r2 = vx * vx + vy * vy + vz * vz;
  const float r = sqrtf(r2);
  const float tt = (r - CENTER_STEP * (float)o) * GAMMA_INV;
  feat[eg][o] = __expf(-tt * tt);
  if (o < 3) {
    const float inv = (r > 1e-10f) ? (1.0f / r) : 0.0f;
    const float comp = (o == 0) ? vx : ((o == 1) ? vy : vz);
    feat[eg][N_BASIS + o] = comp * inv;
  }
  __syncthreads();

  if (valid) {
    float acc = 0.f;
#pragma unroll
    for (int f = 0; f < N_FEAT; ++f) {
      const float* wrow = &Ws[(f * OUT_CH + o) * IN_CH];
      float dot = 0.f;
#pragma unroll
      for (int i = 0; i < IN_CH; ++i) dot += wrow[i] * xs[eg][i];
      acc += feat[eg][f] * dot;
    }
    atomicAdd(&out[dst * OUT_CH + o], acc * INV_SQRT_NNORM);
  }
}

extern "C" void kernel_launch(void* const* d_in, const int* in_sizes, int n_in,
                              void* d_out, int out_size, void* d_ws,
                              size_t ws_size, hipStream_t stream) {
  const float* x = (const float*)d_in[0];        // [n_atoms, 16]
  const float* W = (const float*)d_in[1];        // [19, 16, 16]
  const float* edge_vec = (const float*)d_in[2]; // [E, 3]
  const int* edge_src = (const int*)d_in[3];     // [E]
  const int* edge_dst = (const int*)d_in[4];     // [E]
  float* out = (float*)d_out;

  const int E = in_sizes[3];
  const int n_atoms = in_sizes[0] / IN_CH;

  // out is re-poisoned (0xAA) before every timed launch -> zero it.
  hipMemsetAsync(out, 0, (size_t)out_size * sizeof(float), stream);

  const size_t y_bytes = (size_t)n_atoms * Y_STRIDE * sizeof(float);
  const int edge_blocks = (E + 15) / 16;
  if (ws_size >= y_bytes) {
    float* y = (float*)d_ws;
    precompute_y<<<n_atoms, 320, 0, stream>>>(x, W, y, n_atoms);
    edge_scatter<<<edge_blocks, 256, 0, stream>>>(y, edge_vec, edge_src,
                                                  edge_dst, out, E);
  } else {
    edge_direct<<<edge_blocks, 256, 0, stream>>>(x, W, edge_vec, edge_src,
                                                 edge_dst, out, E);
  }
}

// Round 2
// 83.843 us; speedup vs baseline: 1.1697x; 1.1697x over previous
//
#include <hip/hip_runtime.h>
#include <math.h>

// Problem constants (from reference):
//   B=4, N=1024 -> 4096 atoms; IN_CH=OUT_CH=16; N_BASIS=16; N_FEAT=19
//   centers = linspace(0,3.5,16) -> c_f = f*(3.5/15); GAMMA = 3.5/16
//   out /= sqrt(24)
#define IN_CH 16
#define OUT_CH 16
#define N_BASIS 16
#define N_FEAT 19                    // 16 basis + 3 rhat
#define Y_STRIDE (N_FEAT * OUT_CH)   // 304 floats per atom
#define GAMMA_INV (16.0f / 3.5f)     // 1/GAMMA
#define CENTER_STEP (3.5f / 15.0f)
#define INV_SQRT_NNORM 0.20412414523193154f  // 1/sqrt(24)

// ---------------------------------------------------------------------------
// Kernel A: per-atom pre-contraction  y[a, f, o] = sum_i W[f,o,i] * x[a,i]
// One block per atom; threads t in [0,304) handle (f,o) = (t/16, t%16).
// Also zeroes this atom's 16 output channels (out is poisoned before every
// timed launch) -- saves a separate fill dispatch.
// ---------------------------------------------------------------------------
__global__ __launch_bounds__(320) void precompute_y(
    const float* __restrict__ x, const float* __restrict__ W,
    float* __restrict__ y, float* __restrict__ out, int n_atoms) {
  __shared__ float xs[IN_CH];
  const int a = blockIdx.x;
  const int t = threadIdx.x;
  if (t < IN_CH) {
    xs[t] = x[a * IN_CH + t];
    out[a * OUT_CH + t] = 0.0f;   // zero output slice (poisoned by harness)
  }
  __syncthreads();
  if (t < Y_STRIDE) {
    const float4* w4 = (const float4*)(W + t * IN_CH);
    float acc = 0.f;
#pragma unroll
    for (int q = 0; q < 4; ++q) {
      float4 w = w4[q];
      acc += w.x * xs[4 * q + 0] + w.y * xs[4 * q + 1] +
             w.z * xs[4 * q + 2] + w.w * xs[4 * q + 3];
    }
    y[(size_t)a * Y_STRIDE + t] = acc;
  }
}

// ---------------------------------------------------------------------------
// Kernel B: per-edge  msg[e,o] = sum_f feat[e,f] * y[src_e, f, o]
// 16 lanes per edge (one per output channel), 16 edges per 256-thread block.
// Features shared via LDS (one __expf per lane). After the dot, messages with
// duplicate dst WITHIN the block are merged in LDS (edge list is per-shift
// dst-sorted, so duplicates are common) and only unique (dst,channel) pairs
// issue a global fp32 atomicAdd -- cuts atomic contention.
// ---------------------------------------------------------------------------
__global__ __launch_bounds__(256) void edge_scatter(
    const float* __restrict__ y, const float* __restrict__ edge_vec,
    const int* __restrict__ edge_src, const int* __restrict__ edge_dst,
    float* __restrict__ out, int E) {
  __shared__ float feat[16][N_FEAT];
  __shared__ float msg[16][OUT_CH];
  __shared__ int dsts[16];

  const int t = threadIdx.x;
  const int eg = t >> 4;   // edge slot within block, 0..15
  const int o = t & 15;    // output channel / basis index
  const int e = blockIdx.x * 16 + eg;
  const bool valid = (e < E);

  float vx = 0.f, vy = 0.f, vz = 0.f;
  int src = 0;
  if (valid) {
    vx = edge_vec[3 * e + 0];
    vy = edge_vec[3 * e + 1];
    vz = edge_vec[3 * e + 2];
    src = edge_src[e];
    if (o == 0) dsts[eg] = edge_dst[e];
  } else if (o == 0) {
    dsts[eg] = -1 - eg;  // unique sentinel: never merged, never emitted
  }
  const float r = sqrtf(vx * vx + vy * vy + vz * vz);

  // basis feature o: exp(-((r - c_o)/gamma)^2)
  const float tt = (r - CENTER_STEP * (float)o) * GAMMA_INV;
  feat[eg][o] = __expf(-tt * tt);
  if (o < 3) {
    // reference: rhat = where(r > 1e-10, vec / max(r,1e-10), 0)
    const float inv = (r > 1e-10f) ? (1.0f / r) : 0.0f;
    const float comp = (o == 0) ? vx : ((o == 1) ? vy : vz);
    feat[eg][N_BASIS + o] = comp * inv;
  }
  __syncthreads();

  float acc = 0.f;
  if (valid) {
    const float* __restrict__ yrow = y + (size_t)src * Y_STRIDE + o;
#pragma unroll
    for (int f = 0; f < N_FEAT; ++f) acc += feat[eg][f] * yrow[f * OUT_CH];
  }
  msg[eg][o] = acc;  // 0 for invalid slots
  __syncthreads();

  // Per-block dst dedup: only the first slot with a given dst emits, summing
  // all matching slots' messages for its channel.
  const int mydst = dsts[eg];
  int leader = eg;
#pragma unroll
  for (int j = 0; j < 16; ++j) {
    if (dsts[j] == mydst) { leader = j; break; }
  }
  if (leader == eg && mydst >= 0) {
    float total = 0.f;
#pragma unroll
    for (int j = 0; j < 16; ++j) {
      if (j >= eg && dsts[j] == mydst) total += msg[j][o];
    }
    atomicAdd(&out[mydst * OUT_CH + o], total * INV_SQRT_NNORM);
  }
}

// ---------------------------------------------------------------------------
// Fallback (only if ws_size too small for y): direct per-edge evaluation.
// ---------------------------------------------------------------------------
__global__ __launch_bounds__(256) void edge_direct(
    const float* __restrict__ x, const float* __restrict__ W,
    const float* __restrict__ edge_vec, const int* __restrict__ edge_src,
    const int* __restrict__ edge_dst, float* __restrict__ out, int E) {
  __shared__ float Ws[N_FEAT * OUT_CH * IN_CH];
  __shared__ float feat[16][N_FEAT];
  __shared__ float xs[16][IN_CH];

  const int t = threadIdx.x;
  for (int i = t; i < N_FEAT * OUT_CH * IN_CH; i += 256) Ws[i] = W[i];

  const int eg = t >> 4;
  const int o = t & 15;
  const int e = blockIdx.x * 16 + eg;
  const bool valid = (e < E);

  float vx = 0.f, vy = 0.f, vz = 0.f;
  int src = 0, dst = 0;
  if (valid) {
    vx = edge_vec[3 * e + 0];
    vy = edge_vec[3 * e + 1];
    vz = edge_vec[3 * e + 2];
    src = edge_src[e];
    dst = edge_dst[e];
    xs[eg][o] = x[src * IN_CH + o];
  }
  const float r = sqrtf(vx * vx + vy * vy + vz * vz);
  const float tt = (r - CENTER_STEP * (float)o) * GAMMA_INV;
  feat[eg][o] = __expf(-tt * tt);
  if (o < 3) {
    const float inv = (r > 1e-10f) ? (1.0f / r) : 0.0f;
    const float comp = (o == 0) ? vx : ((o == 1) ? vy : vz);
    feat[eg][N_BASIS + o] = comp * inv;
  }
  __syncthreads();

  if (valid) {
    float acc = 0.f;
#pragma unroll
    for (int f = 0; f < N_FEAT; ++f) {
      const float* wrow = &Ws[(f * OUT_CH + o) * IN_CH];
      float dot = 0.f;
#pragma unroll
      for (int i = 0; i < IN_CH; ++i) dot += wrow[i] * xs[eg][i];
      acc += feat[eg][f] * dot;
    }
    atomicAdd(&out[dst * OUT_CH + o], acc * INV_SQRT_NNORM);
  }
}

extern "C" void kernel_launch(void* const* d_in, const int* in_sizes, int n_in,
                              void* d_out, int out_size, void* d_ws,
                              size_t ws_size, hipStream_t stream) {
  const float* x = (const float*)d_in[0];        // [n_atoms, 16]
  const float* W = (const float*)d_in[1];        // [19, 16, 16]
  const float* edge_vec = (const float*)d_in[2]; // [E, 3]
  const int* edge_src = (const int*)d_in[3];     // [E]
  const int* edge_dst = (const int*)d_in[4];     // [E]
  float* out = (float*)d_out;

  const int E = in_sizes[3];
  const int n_atoms = in_sizes[0] / IN_CH;

  const size_t y_bytes = (size_t)n_atoms * Y_STRIDE * sizeof(float);
  const int edge_blocks = (E + 15) / 16;
  if (ws_size >= y_bytes) {
    float* y = (float*)d_ws;
    precompute_y<<<n_atoms, 320, 0, stream>>>(x, W, y, out, n_atoms);
    edge_scatter<<<edge_blocks, 256, 0, stream>>>(y, edge_vec, edge_src,
                                                  edge_dst, out, E);
  } else {
    hipMemsetAsync(out, 0, (size_t)out_size * sizeof(float), stream);
    edge_direct<<<edge_blocks, 256, 0, stream>>>(x, W, edge_vec, edge_src,
                                                 edge_dst, out, E);
  }
}